// Round 7
// baseline (185.791 us; speedup 1.0000x reference)
//
#include <hip/hip_runtime.h>
#include <math.h>

// WfcNN: B=262144.
//   h1 = tanh(x @ W0 + b0)            (B,128)
//   h2 = tanh(h1 @ W1 + b1)           (B,64)
//   g  = tanh(h2 . Wa[eid] + ba[eid]) (B,32)
//   psi= g . Wb[eid] + bb[eid]        (B,2) ; out = psi / sqrt(|psi|^2+1e-6)
//
// Round 16: grid-size experiment. Across R0..R6 the non-wfc time (60 vs
// 79-99us) anti-correlates with ONE variable: wfc grid 1056 vs 4126 blocks
// -- never with prologue atomics/dispatch-count/write volume (all varied,
// all refuted). Hypothesis: per-workgroup dispatch/retire cost (~8-10ns x
// ~3000 extra wgs) attributed outside kernel durations.
// This round: R0 prologue VERBATIM (HB=128 hist+scatter, unpadded etot,
// memset; measured non-wfc=60us) + proven 1-wave wfc body VERBATIM, but
// each wfc block processes SEGS=4 consecutive 64-sample segments
// sequentially => grid 1032 (= R0's block count), descriptors derived
// in-block from LDS-cached etot (no desc table, no desc block).
// Consecutive segments share experts -> Wa frags L1-hot.
// Cooperative fusion FAILED in R8 -- do not retry.

#define THREADS 64        // wfc block = 1 wave; processes SEGS*64 samples
#define NE 30
#define HB 128            // hist/scatter blocks (R0-proven)
#define SEGS 4
#define WFCBLK 1032       // ceil(4126/4); covers all segments
#define SA 67             // u32 row stride for [k][sample] staging (64+3)
#define SG 36             // f32 row stride for [sample][h] g staging

typedef short bf16x8 __attribute__((ext_vector_type(8)));
typedef float f32x4 __attribute__((ext_vector_type(4)));

__device__ __forceinline__ int expert_id(int nn, int ll, int mm) {
    return ((nn - 1) * nn * (2 * nn - 1)) / 6 + ll * ll + ll + mm;
}

// tanh(v) = 1 - 2/(exp2(2*log2e*v)+1); saturates correctly, no clamp.
__device__ __forceinline__ float fast_tanh(float v) {
    float e = __builtin_exp2f(v * 2.885390082f);
    return fmaf(-2.0f, __builtin_amdgcn_rcpf(e + 1.0f), 1.0f);
}

__device__ __forceinline__ unsigned int f2b(float f) {   // f32 -> bf16 RNE
    unsigned int u = __float_as_uint(f);
    return (u + 0x7fffu + ((u >> 16) & 1u)) >> 16;
}
__device__ __forceinline__ float b2f(unsigned int b) {
    return __uint_as_float(b << 16);
}
// runtime split: RNE hi, truncated lo; packed (lo16<<16)|hi16
__device__ __forceinline__ unsigned int packsplit(float v) {
    const unsigned int hb = f2b(v);
    const float lo = v - b2f(hb);
    return (__float_as_uint(lo) & 0xffff0000u) | hb;
}

union U8 { unsigned int u[4]; bf16x8 v; };
// packed words -> hi-plane / lo-plane bf16x8 (bit-identical to shift/mask form)
__device__ __forceinline__ void unpack8(const unsigned int* w, bf16x8& hi, bf16x8& lo) {
    U8 H, L;
#pragma unroll
    for (int i = 0; i < 4; ++i) {
        H.u[i] = __builtin_amdgcn_perm(w[2 * i + 1], w[2 * i], 0x05040100u);
        L.u[i] = __builtin_amdgcn_perm(w[2 * i + 1], w[2 * i], 0x07060302u);
    }
    hi = H.v; lo = L.v;
}

// ---- K1: hist + eid cache + bucket base reservation + weight splitting ----
// VERBATIM R0 structure (HB=128, unpadded etot reservation).
__global__ void hist_pack_kernel(const int* __restrict__ nq, const int* __restrict__ lq,
                                 const int* __restrict__ mq,
                                 int* __restrict__ eids, int* __restrict__ etot,
                                 int* __restrict__ bbase,
                                 const float* __restrict__ W1,
                                 unsigned short* __restrict__ W1fh, unsigned short* __restrict__ W1fl,
                                 const float* __restrict__ Wa,
                                 unsigned short* __restrict__ Wafh, unsigned short* __restrict__ Wafl,
                                 int B) {
    const int tid = threadIdx.x;
    const int bx = blockIdx.x;
    if (bx < HB) {
        __shared__ int h[NE];
        if (tid < NE) h[tid] = 0;
        __syncthreads();
        const int per = B / HB, base = bx * per;
        for (int i = tid; i < per; i += blockDim.x) {
            const int e = expert_id(nq[base + i], lq[base + i], mq[base + i]);
            eids[base + i] = e;
            atomicAdd(&h[e], 1);
        }
        __syncthreads();
        if (tid < NE) bbase[bx * NE + tid] = atomicAdd(&etot[tid], h[tid]);
    } else if (bx == HB) {
        // W1 (128,64) -> hi/lo planes in B-frag order (rec=((c*4+nt)*4+qd)*16+l16)
        for (int i = tid; i < 8192; i += blockDim.x) {
            const int j = i & 7, s = (i >> 3) & 15, q = (i >> 7) & 3;
            const int nt = (i >> 9) & 3, c = i >> 11;
            const int k = c * 32 + q * 8 + j, n = nt * 16 + s;
            const float w = W1[k * 64 + n];
            const unsigned int hb = f2b(w);
            W1fh[i] = (unsigned short)hb;
            W1fl[i] = (unsigned short)f2b(w - b2f(hb));
        }
    } else {
        // Wa[e] (64,32) -> hi/lo planes (rec=((c2*2+nt2)*4+qd)*16+l16)
        const int e = bx - HB - 1;
        for (int i = tid; i < 2048; i += blockDim.x) {
            const int j = i & 7, s = (i >> 3) & 15, q = (i >> 7) & 3;
            const int nt2 = (i >> 9) & 1, c2 = (i >> 10) & 1;
            const int d = c2 * 32 + q * 8 + j, hh = nt2 * 16 + s;
            const float w = Wa[e * 2048 + d * 32 + hh];
            const unsigned int hb = f2b(w);
            Wafh[e * 2048 + i] = (unsigned short)hb;
            Wafl[e * 2048 + i] = (unsigned short)f2b(w - b2f(hb));
        }
    }
}

// ---- K2: scatter into sorted order (VERBATIM R0 structure) ----
__global__ void scatter_kernel(const int* __restrict__ eids, const int* __restrict__ etot,
                               const int* __restrict__ bbase, int* __restrict__ perm, int B) {
    __shared__ int lcnt[NE], esrt[NE], bb[NE];
    const int tid = threadIdx.x;
    if (tid < NE) { lcnt[tid] = 0; bb[tid] = bbase[blockIdx.x * NE + tid]; }
    if (tid == 0) {
        int es = 0;
        for (int e = 0; e < NE; ++e) { esrt[e] = es; es += etot[e]; }
    }
    __syncthreads();
    const int per = B / gridDim.x;
    const int blk = blockIdx.x * per;
    for (int i = tid; i < per; i += blockDim.x) {
        const int idx = blk + i;
        const int e = eids[idx];
        const int r = atomicAdd(&lcnt[e], 1);
        perm[esrt[e] + bb[e] + r] = idx;
    }
}

// ---- K3: fused MLP; layer2 + expert-A on MFMA (3-pass split-bf16) ----
// 1 wave per block; SEGS=4 consecutive 64-sample segments per block
// (grid 1032 = R0's block count). Segment descriptors derived from
// LDS-cached etot. Compute body bit-identical to the proven 55us kernel.
__global__ __launch_bounds__(THREADS, 4) void wfc_kernel(
    const float* __restrict__ x, const int* __restrict__ perm,
    const int* __restrict__ etot,
    const float* __restrict__ W0, const float* __restrict__ b0,
    const bf16x8* __restrict__ W1fh, const bf16x8* __restrict__ W1fl,
    const float* __restrict__ b1,
    const bf16x8* __restrict__ Wafh, const bf16x8* __restrict__ Wafl,
    const float* __restrict__ ba,
    const float* __restrict__ Wb, const float* __restrict__ bb,
    float* __restrict__ out)
{
    __shared__ unsigned int sbuf[2304];      // max(32*SA, 64*SG) u32 = 9216 B
    __shared__ int etl[NE];

    const int tid = threadIdx.x;
    if (tid < NE) etl[tid] = etot[tid];
    __syncthreads();

    const int lane = tid & 63;
    const int wv   = tid >> 6;               // always 0 (1 wave); kept generic
    const int qd   = lane >> 4;
    const int l16  = lane & 15;

    for (int s = 0; s < SEGS; ++s) {
        const int gid = blockIdx.x * SEGS + s;

        // derive (eid, start, cnt) for segment gid from LDS etot (~30 iters)
        int eid = -1, start = 0, cnt = 0;
        {
            int cum = 0, es = 0;
#pragma unroll 1
            for (int e = 0; e < NE; ++e) {
                const int t = etl[e];
                const int nb = (t + 63) >> 6;
                if (gid < cum + nb) {
                    const int seg = gid - cum;
                    eid = e; start = es + (seg << 6); cnt = min(64, t - (seg << 6));
                    break;
                }
                cum += nb; es += t;
            }
        }
        if (eid < 0) break;                  // past last segment: no more work
        eid = __builtin_amdgcn_readfirstlane(eid);

        const bool valid = tid < cnt;
        const int idx = perm[start + (valid ? tid : 0)];

        const float x0 = x[idx * 3 + 0];
        const float x1 = x[idx * 3 + 1];
        const float x2 = x[idx * 3 + 2];

        // ---- layer 2 accumulators, init b1 (C layout: col = l16) ----
        f32x4 acc[4][4];
#pragma unroll
        for (int nt = 0; nt < 4; ++nt) {
            const float bv = b1[nt * 16 + l16];
#pragma unroll
            for (int mt = 0; mt < 4; ++mt) {
                f32x4 c; c[0] = bv; c[1] = bv; c[2] = bv; c[3] = bv;
                acc[mt][nt] = c;
            }
        }

        // ---- layer-2 GEMM: 4 K-chunks of 32 ----
        for (int c = 0; c < 4; ++c) {
            __syncthreads();                 // also covers inter-segment sbuf reuse
#pragma unroll
            for (int kk = 0; kk < 32; ++kk) {
                const int k = c * 32 + kk;
                const float pre = fmaf(x0, W0[k], fmaf(x1, W0[128 + k], fmaf(x2, W0[256 + k], b0[k])));
                sbuf[kk * SA + tid] = packsplit(fast_tanh(pre));
            }
            __syncthreads();

            bf16x8 Bhi[4], Blo[4];
#pragma unroll
            for (int nt = 0; nt < 4; ++nt) {
                const int rec = (c * 4 + nt) * 64 + qd * 16 + l16;
                Bhi[nt] = W1fh[rec];
                Blo[nt] = W1fl[rec];
            }
#pragma unroll
            for (int mt = 0; mt < 4; ++mt) {
                unsigned int a[8];
                const int mrow = wv * 64 + mt * 16 + l16;
#pragma unroll
                for (int j = 0; j < 8; ++j) a[j] = sbuf[(qd * 8 + j) * SA + mrow];
                bf16x8 Ahi, Alo;
                unpack8(a, Ahi, Alo);
#pragma unroll
                for (int nt = 0; nt < 4; ++nt) {
                    acc[mt][nt] = __builtin_amdgcn_mfma_f32_16x16x32_bf16(Ahi, Bhi[nt], acc[mt][nt], 0, 0, 0);
                    acc[mt][nt] = __builtin_amdgcn_mfma_f32_16x16x32_bf16(Ahi, Blo[nt], acc[mt][nt], 0, 0, 0);
                    acc[mt][nt] = __builtin_amdgcn_mfma_f32_16x16x32_bf16(Alo, Bhi[nt], acc[mt][nt], 0, 0, 0);
                }
            }
        }

        // ---- expert-A accumulators, init ba ----
        f32x4 acc2[4][2];
#pragma unroll
        for (int nt2 = 0; nt2 < 2; ++nt2) {
            const float bv = ba[(eid << 5) + nt2 * 16 + l16];
#pragma unroll
            for (int mt = 0; mt < 4; ++mt) {
                f32x4 c; c[0] = bv; c[1] = bv; c[2] = bv; c[3] = bv;
                acc2[mt][nt2] = c;
            }
        }

        // ---- expert-A GEMM: h2 = tanh(acc) restaged [d][sample]; 2 K-chunks ----
        const bf16x8* __restrict__ waeh = Wafh + (eid << 8);
        const bf16x8* __restrict__ wael = Wafl + (eid << 8);
        for (int c2 = 0; c2 < 2; ++c2) {
            __syncthreads();
#pragma unroll
            for (int mt = 0; mt < 4; ++mt) {
#pragma unroll
                for (int ntl = 0; ntl < 2; ++ntl) {
#pragma unroll
                    for (int r = 0; r < 4; ++r) {
                        const float h2 = fast_tanh(acc[mt][c2 * 2 + ntl][r]);
                        const int dl  = ntl * 16 + l16;
                        const int row = wv * 64 + mt * 16 + qd * 4 + r;
                        sbuf[dl * SA + row] = packsplit(h2);
                    }
                }
            }
            __syncthreads();

            bf16x8 B2hi[2], B2lo[2];
#pragma unroll
            for (int nt2 = 0; nt2 < 2; ++nt2) {
                const int rec = (c2 * 2 + nt2) * 64 + qd * 16 + l16;
                B2hi[nt2] = waeh[rec];
                B2lo[nt2] = wael[rec];
            }
#pragma unroll
            for (int mt = 0; mt < 4; ++mt) {
                unsigned int a[8];
                const int mrow = wv * 64 + mt * 16 + l16;
#pragma unroll
                for (int j = 0; j < 8; ++j) a[j] = sbuf[(qd * 8 + j) * SA + mrow];
                bf16x8 Ahi, Alo;
                unpack8(a, Ahi, Alo);
#pragma unroll
                for (int nt2 = 0; nt2 < 2; ++nt2) {
                    acc2[mt][nt2] = __builtin_amdgcn_mfma_f32_16x16x32_bf16(Ahi, B2hi[nt2], acc2[mt][nt2], 0, 0, 0);
                    acc2[mt][nt2] = __builtin_amdgcn_mfma_f32_16x16x32_bf16(Ahi, B2lo[nt2], acc2[mt][nt2], 0, 0, 0);
                    acc2[mt][nt2] = __builtin_amdgcn_mfma_f32_16x16x32_bf16(Alo, B2hi[nt2], acc2[mt][nt2], 0, 0, 0);
                }
            }
        }

        // ---- g = tanh(acc2) staged [sample][h], expert-B per-thread ----
        __syncthreads();
        float* g2 = (float*)sbuf;
#pragma unroll
        for (int mt = 0; mt < 4; ++mt) {
#pragma unroll
            for (int nt2 = 0; nt2 < 2; ++nt2) {
#pragma unroll
                for (int r = 0; r < 4; ++r) {
                    const int row = wv * 64 + mt * 16 + qd * 4 + r;
                    g2[row * SG + nt2 * 16 + l16] = fast_tanh(acc2[mt][nt2][r]);
                }
            }
        }
        __syncthreads();

        float gv[32];
        {
            const float4* grow = (const float4*)(g2 + tid * SG);
#pragma unroll
            for (int i = 0; i < 8; ++i) {
                float4 v = grow[i];
                gv[4 * i + 0] = v.x; gv[4 * i + 1] = v.y;
                gv[4 * i + 2] = v.z; gv[4 * i + 3] = v.w;
            }
        }

        const float* __restrict__ wbe = Wb + (eid << 6);
        float p0 = bb[2 * eid], p1 = bb[2 * eid + 1];
#pragma unroll
        for (int h = 0; h < 32; ++h) {
            p0 = fmaf(gv[h], wbe[2 * h + 0], p0);
            p1 = fmaf(gv[h], wbe[2 * h + 1], p1);
        }

        const float sq = fmaf(p0, p0, fmaf(p1, p1, 1e-6f));
        const float inv = 1.0f / sqrtf(sq);
        if (valid) {
            float2 o; o.x = p0 * inv; o.y = p1 * inv;
            ((float2*)out)[idx] = o;
        }
    }
}

extern "C" void kernel_launch(void* const* d_in, const int* in_sizes, int n_in,
                              void* d_out, int out_size, void* d_ws, size_t ws_size,
                              hipStream_t stream) {
    const float* x  = (const float*)d_in[0];
    const int*   n  = (const int*)d_in[1];
    const int*   l  = (const int*)d_in[2];
    const int*   m  = (const int*)d_in[3];
    const float* W0 = (const float*)d_in[4];
    const float* b0 = (const float*)d_in[5];
    const float* W1 = (const float*)d_in[6];
    const float* b1 = (const float*)d_in[7];
    const float* Wa = (const float*)d_in[8];
    const float* ba = (const float*)d_in[9];
    const float* Wb = (const float*)d_in[10];
    const float* bb = (const float*)d_in[11];
    float* out = (float*)d_out;

    const int B = in_sizes[1];   // 262144

    // workspace layout (all segments 16B aligned)
    int*            perm  = (int*)d_ws;                      // B
    int*            eids  = perm + B;                        // B
    int*            bbase = eids + B;                        // HB*NE = 3840
    int*            etot  = bbase + HB * NE;                 // 32
    unsigned short* W1fh  = (unsigned short*)(etot + 32);    // 8192 u16
    unsigned short* W1fl  = W1fh + 8192;                     // 8192 u16
    unsigned short* Wafh  = W1fl + 8192;                     // 30*2048 u16
    unsigned short* Wafl  = Wafh + NE * 2048;                // 30*2048 u16

    hipMemsetAsync(etot, 0, 32 * sizeof(int), stream);
    hist_pack_kernel<<<HB + 1 + NE, 256, 0, stream>>>(
        n, l, m, eids, etot, bbase, W1, W1fh, W1fl, Wa, Wafh, Wafl, B);
    scatter_kernel<<<HB, 256, 0, stream>>>(eids, etot, bbase, perm, B);
    wfc_kernel<<<WFCBLK, THREADS, 0, stream>>>(
        x, perm, etot, W0, b0,
        (const bf16x8*)W1fh, (const bf16x8*)W1fl, b1,
        (const bf16x8*)Wafh, (const bf16x8*)Wafl, ba, Wb, bb, out);
}

// Round 8
// 158.626 us; speedup vs baseline: 1.1713x; 1.1713x over previous
//
#include <hip/hip_runtime.h>
#include <math.h>

// WfcNN: B=262144.
//   h1 = tanh(x @ W0 + b0)            (B,128)
//   h2 = tanh(h1 @ W1 + b1)           (B,64)
//   g  = tanh(h2 . Wa[eid] + ba[eid]) (B,32)
//   psi= g . Wb[eid] + bb[eid]        (B,2) ; out = psi / sqrt(|psi|^2+1e-6)
//
// Round 17: minimum-dispatch pipeline.
//  R16 post-mortem: SEGS=4 collapsed occupancy (8%, wfc 100us) AND refuted
//  the grid-size theory for non-wfc time (R0 prologue verbatim still ~86us).
//  Across R0..R7 the only structural signal: 3 dispatches -> non-wfc 79-81,
//  4 dispatches -> 92-99 => ~15us fixed cost per dispatch + env noise.
//  This round: memset(4B) + ONE fused prologue kernel + wfc.
//   fused: 256 hist blocks (LDS hist, rank kept in 4 REGISTERS -- no eidr
//     array) publish cnt[blk][e] with release stores + threadfence, bump a
//     done counter, spin until done==256 (co-residency guaranteed: 287
//     blocks x 256 thr x 31KB LDS on 256 CUs), then derive own bases from
//     the cnt matrix (R6-proven scan) and scatter from registers. 31 weight
//     pack blocks ride along, no barrier. Agent-scope atomics for cross-XCD
//     visibility of cnt.
//   wfc: PROVEN 55us config (4126 x 1 wave, perm + x gather) with R0-proven
//     in-kernel etot scan (no desc table).
// Cooperative fusion via hipLaunchCooperativeKernel FAILED in R8 (harness)
// -- this uses a resident-grid spin barrier instead.

#define THREADS 64        // wfc block = 1 wave = 64 samples
#define NE 30
#define HB 256            // hist blocks; PER = B/HB = 1024
#define PER 1024
#define MAXBLK 4126       // 262144/64 + 30 partial blocks
#define SA 67             // u32 row stride for [k][sample] staging (64+3)
#define SG 36             // f32 row stride for [sample][h] g staging

typedef short bf16x8 __attribute__((ext_vector_type(8)));
typedef float f32x4 __attribute__((ext_vector_type(4)));

__device__ __forceinline__ int expert_id(int nn, int ll, int mm) {
    return ((nn - 1) * nn * (2 * nn - 1)) / 6 + ll * ll + ll + mm;
}

// tanh(v) = 1 - 2/(exp2(2*log2e*v)+1); saturates correctly, no clamp.
__device__ __forceinline__ float fast_tanh(float v) {
    float e = __builtin_exp2f(v * 2.885390082f);
    return fmaf(-2.0f, __builtin_amdgcn_rcpf(e + 1.0f), 1.0f);
}

__device__ __forceinline__ unsigned int f2b(float f) {   // f32 -> bf16 RNE
    unsigned int u = __float_as_uint(f);
    return (u + 0x7fffu + ((u >> 16) & 1u)) >> 16;
}
__device__ __forceinline__ float b2f(unsigned int b) {
    return __uint_as_float(b << 16);
}
// runtime split: RNE hi, truncated lo; packed (lo16<<16)|hi16
__device__ __forceinline__ unsigned int packsplit(float v) {
    const unsigned int hb = f2b(v);
    const float lo = v - b2f(hb);
    return (__float_as_uint(lo) & 0xffff0000u) | hb;
}

union U8 { unsigned int u[4]; bf16x8 v; };
// packed words -> hi-plane / lo-plane bf16x8 (bit-identical to shift/mask form)
__device__ __forceinline__ void unpack8(const unsigned int* w, bf16x8& hi, bf16x8& lo) {
    U8 H, L;
#pragma unroll
    for (int i = 0; i < 4; ++i) {
        H.u[i] = __builtin_amdgcn_perm(w[2 * i + 1], w[2 * i], 0x05040100u);
        L.u[i] = __builtin_amdgcn_perm(w[2 * i + 1], w[2 * i], 0x07060302u);
    }
    hi = H.v; lo = L.v;
}

// ---- K1: fused hist + resident-grid barrier + scatter + weight packing ----
__global__ void fused_prologue(const int* __restrict__ nq, const int* __restrict__ lq,
                               const int* __restrict__ mq,
                               int* __restrict__ cnt, int* __restrict__ done,
                               int* __restrict__ etot, int* __restrict__ perm,
                               const float* __restrict__ W1,
                               unsigned short* __restrict__ W1fh, unsigned short* __restrict__ W1fl,
                               const float* __restrict__ Wa,
                               unsigned short* __restrict__ Wafh, unsigned short* __restrict__ Wafl,
                               int B) {
    const int tid = threadIdx.x;
    const int bx = blockIdx.x;

    if (bx < HB) {
        __shared__ int h[NE];
        __shared__ int cl[HB * NE];          // 30720 B
        __shared__ int bb[NE], tq[NE], esrt[NE];
        if (tid < NE) h[tid] = 0;
        __syncthreads();

        // hist; rank kept in registers (PER/256 = 4 items per thread)
        const int base = bx * PER;
        int pk[4];
#pragma unroll
        for (int j = 0; j < 4; ++j) {
            const int i = base + tid + j * 256;
            const int e = expert_id(nq[i], lq[i], mq[i]);
            const int r = atomicAdd(&h[e], 1);       // LDS
            pk[j] = (r << 5) | e;                    // r < 1024, e < 30
        }
        __syncthreads();

        // publish counts (agent scope, release)
        if (tid < NE)
            __hip_atomic_store(&cnt[bx * NE + tid], h[tid],
                               __ATOMIC_RELEASE, __HIP_MEMORY_SCOPE_AGENT);
        __syncthreads();
        if (tid == 0) {
            __threadfence();
            atomicAdd(done, 1);                      // device scope
            while (__hip_atomic_load(done, __ATOMIC_ACQUIRE,
                                     __HIP_MEMORY_SCOPE_AGENT) < HB) {
                __builtin_amdgcn_s_sleep(8);
            }
        }
        __syncthreads();

        // load full count matrix (agent-scope loads bypass stale caches)
        for (int i = tid; i < HB * NE; i += 256)
            cl[i] = __hip_atomic_load(&cnt[i], __ATOMIC_RELAXED,
                                      __HIP_MEMORY_SCOPE_AGENT);
        __syncthreads();

        // per-expert column scan: own base (blocks < bx) + expert totals
        if (tid < NE) {
            int s = 0, mybase = 0;
#pragma unroll 4
            for (int blk = 0; blk < HB; ++blk) {
                if (blk == bx) mybase = s;
                s += cl[blk * NE + tid];
            }
            bb[tid] = mybase;
            tq[tid] = s;
        }
        __syncthreads();
        if (tid == 0) {
            int es = 0;
            for (int e = 0; e < NE; ++e) { esrt[e] = es; es += tq[e]; }
        }
        __syncthreads();
        if (bx == 0 && tid < NE) etot[tid] = tq[tid];   // for wfc (kernel boundary)

        // scatter own 4 samples from registers
#pragma unroll
        for (int j = 0; j < 4; ++j) {
            const int e = pk[j] & 31;
            perm[esrt[e] + bb[e] + (pk[j] >> 5)] = base + tid + j * 256;
        }
    } else if (bx == HB) {
        // W1 (128,64) -> hi/lo planes in B-frag order (rec=((c*4+nt)*4+qd)*16+l16)
        for (int i = tid; i < 8192; i += blockDim.x) {
            const int j = i & 7, s = (i >> 3) & 15, q = (i >> 7) & 3;
            const int nt = (i >> 9) & 3, c = i >> 11;
            const int k = c * 32 + q * 8 + j, n = nt * 16 + s;
            const float w = W1[k * 64 + n];
            const unsigned int hb = f2b(w);
            W1fh[i] = (unsigned short)hb;
            W1fl[i] = (unsigned short)f2b(w - b2f(hb));
        }
    } else {
        // Wa[e] (64,32) -> hi/lo planes (rec=((c2*2+nt2)*4+qd)*16+l16)
        const int e = bx - HB - 1;
        for (int i = tid; i < 2048; i += blockDim.x) {
            const int j = i & 7, s = (i >> 3) & 15, q = (i >> 7) & 3;
            const int nt2 = (i >> 9) & 1, c2 = (i >> 10) & 1;
            const int d = c2 * 32 + q * 8 + j, hh = nt2 * 16 + s;
            const float w = Wa[e * 2048 + d * 32 + hh];
            const unsigned int hb = f2b(w);
            Wafh[e * 2048 + i] = (unsigned short)hb;
            Wafl[e * 2048 + i] = (unsigned short)f2b(w - b2f(hb));
        }
    }
}

// ---- K2: fused MLP; layer2 + expert-A on MFMA (3-pass split-bf16) ----
// 64 threads = 1 wave = 64 samples (PROVEN 55us config); (eid,start,cnt)
// derived from etot via the R0-proven 30-iter scan.
__global__ __launch_bounds__(THREADS, 4) void wfc_kernel(
    const float* __restrict__ x, const int* __restrict__ perm,
    const int* __restrict__ etot,
    const float* __restrict__ W0, const float* __restrict__ b0,
    const bf16x8* __restrict__ W1fh, const bf16x8* __restrict__ W1fl,
    const float* __restrict__ b1,
    const bf16x8* __restrict__ Wafh, const bf16x8* __restrict__ Wafl,
    const float* __restrict__ ba,
    const float* __restrict__ Wb, const float* __restrict__ bb,
    float* __restrict__ out)
{
    __shared__ unsigned int sbuf[2304];      // max(32*SA, 64*SG) u32 = 9216 B

    // derive (eid, start, cnt): uniform scalar 30-iter scan (R0-proven)
    int eid = -1, start = 0, cnt = 0;
    {
        int cum = 0, es = 0;
#pragma unroll 1
        for (int e = 0; e < NE; ++e) {
            const int t = etot[e];
            const int nb = (t + 63) >> 6;
            if ((int)blockIdx.x < cum + nb) {
                const int seg = blockIdx.x - cum;
                eid = e; start = es + (seg << 6); cnt = min(64, t - (seg << 6));
                break;
            }
            cum += nb; es += t;
        }
    }
    if (eid < 0) return;
    eid = __builtin_amdgcn_readfirstlane(eid);

    const int tid = threadIdx.x;
    const bool valid = tid < cnt;
    const int idx = perm[start + (valid ? tid : 0)];

    const int lane = tid & 63;
    const int wv   = tid >> 6;               // always 0 (1 wave); kept generic
    const int qd   = lane >> 4;
    const int l16  = lane & 15;

    const float x0 = x[idx * 3 + 0];
    const float x1 = x[idx * 3 + 1];
    const float x2 = x[idx * 3 + 2];

    // ---- layer 2 accumulators, init b1 (C layout: col = l16) ----
    f32x4 acc[4][4];
#pragma unroll
    for (int nt = 0; nt < 4; ++nt) {
        const float bv = b1[nt * 16 + l16];
#pragma unroll
        for (int mt = 0; mt < 4; ++mt) {
            f32x4 c; c[0] = bv; c[1] = bv; c[2] = bv; c[3] = bv;
            acc[mt][nt] = c;
        }
    }

    // ---- layer-2 GEMM: 4 K-chunks of 32 ----
    for (int c = 0; c < 4; ++c) {
        if (c) __syncthreads();
#pragma unroll
        for (int kk = 0; kk < 32; ++kk) {
            const int k = c * 32 + kk;
            const float pre = fmaf(x0, W0[k], fmaf(x1, W0[128 + k], fmaf(x2, W0[256 + k], b0[k])));
            sbuf[kk * SA + tid] = packsplit(fast_tanh(pre));
        }
        __syncthreads();

        bf16x8 Bhi[4], Blo[4];
#pragma unroll
        for (int nt = 0; nt < 4; ++nt) {
            const int rec = (c * 4 + nt) * 64 + qd * 16 + l16;
            Bhi[nt] = W1fh[rec];
            Blo[nt] = W1fl[rec];
        }
#pragma unroll
        for (int mt = 0; mt < 4; ++mt) {
            unsigned int a[8];
            const int mrow = wv * 64 + mt * 16 + l16;
#pragma unroll
            for (int j = 0; j < 8; ++j) a[j] = sbuf[(qd * 8 + j) * SA + mrow];
            bf16x8 Ahi, Alo;
            unpack8(a, Ahi, Alo);
#pragma unroll
            for (int nt = 0; nt < 4; ++nt) {
                acc[mt][nt] = __builtin_amdgcn_mfma_f32_16x16x32_bf16(Ahi, Bhi[nt], acc[mt][nt], 0, 0, 0);
                acc[mt][nt] = __builtin_amdgcn_mfma_f32_16x16x32_bf16(Ahi, Blo[nt], acc[mt][nt], 0, 0, 0);
                acc[mt][nt] = __builtin_amdgcn_mfma_f32_16x16x32_bf16(Alo, Bhi[nt], acc[mt][nt], 0, 0, 0);
            }
        }
    }

    // ---- expert-A accumulators, init ba ----
    f32x4 acc2[4][2];
#pragma unroll
    for (int nt2 = 0; nt2 < 2; ++nt2) {
        const float bv = ba[(eid << 5) + nt2 * 16 + l16];
#pragma unroll
        for (int mt = 0; mt < 4; ++mt) {
            f32x4 c; c[0] = bv; c[1] = bv; c[2] = bv; c[3] = bv;
            acc2[mt][nt2] = c;
        }
    }

    // ---- expert-A GEMM: h2 = tanh(acc) restaged [d][sample]; 2 K-chunks ----
    const bf16x8* __restrict__ waeh = Wafh + (eid << 8);
    const bf16x8* __restrict__ wael = Wafl + (eid << 8);
    for (int c2 = 0; c2 < 2; ++c2) {
        __syncthreads();
#pragma unroll
        for (int mt = 0; mt < 4; ++mt) {
#pragma unroll
            for (int ntl = 0; ntl < 2; ++ntl) {
#pragma unroll
                for (int r = 0; r < 4; ++r) {
                    const float h2 = fast_tanh(acc[mt][c2 * 2 + ntl][r]);
                    const int dl  = ntl * 16 + l16;
                    const int row = wv * 64 + mt * 16 + qd * 4 + r;
                    sbuf[dl * SA + row] = packsplit(h2);
                }
            }
        }
        __syncthreads();

        bf16x8 B2hi[2], B2lo[2];
#pragma unroll
        for (int nt2 = 0; nt2 < 2; ++nt2) {
            const int rec = (c2 * 2 + nt2) * 64 + qd * 16 + l16;
            B2hi[nt2] = waeh[rec];
            B2lo[nt2] = wael[rec];
        }
#pragma unroll
        for (int mt = 0; mt < 4; ++mt) {
            unsigned int a[8];
            const int mrow = wv * 64 + mt * 16 + l16;
#pragma unroll
            for (int j = 0; j < 8; ++j) a[j] = sbuf[(qd * 8 + j) * SA + mrow];
            bf16x8 Ahi, Alo;
            unpack8(a, Ahi, Alo);
#pragma unroll
            for (int nt2 = 0; nt2 < 2; ++nt2) {
                acc2[mt][nt2] = __builtin_amdgcn_mfma_f32_16x16x32_bf16(Ahi, B2hi[nt2], acc2[mt][nt2], 0, 0, 0);
                acc2[mt][nt2] = __builtin_amdgcn_mfma_f32_16x16x32_bf16(Ahi, B2lo[nt2], acc2[mt][nt2], 0, 0, 0);
                acc2[mt][nt2] = __builtin_amdgcn_mfma_f32_16x16x32_bf16(Alo, B2hi[nt2], acc2[mt][nt2], 0, 0, 0);
            }
        }
    }

    // ---- g = tanh(acc2) staged [sample][h], expert-B per-thread ----
    __syncthreads();
    float* g2 = (float*)sbuf;
#pragma unroll
    for (int mt = 0; mt < 4; ++mt) {
#pragma unroll
        for (int nt2 = 0; nt2 < 2; ++nt2) {
#pragma unroll
            for (int r = 0; r < 4; ++r) {
                const int row = wv * 64 + mt * 16 + qd * 4 + r;
                g2[row * SG + nt2 * 16 + l16] = fast_tanh(acc2[mt][nt2][r]);
            }
        }
    }
    __syncthreads();

    float gv[32];
    {
        const float4* grow = (const float4*)(g2 + tid * SG);
#pragma unroll
        for (int i = 0; i < 8; ++i) {
            float4 v = grow[i];
            gv[4 * i + 0] = v.x; gv[4 * i + 1] = v.y;
            gv[4 * i + 2] = v.z; gv[4 * i + 3] = v.w;
        }
    }

    const float* __restrict__ wbe = Wb + (eid << 6);
    float p0 = bb[2 * eid], p1 = bb[2 * eid + 1];
#pragma unroll
    for (int h = 0; h < 32; ++h) {
        p0 = fmaf(gv[h], wbe[2 * h + 0], p0);
        p1 = fmaf(gv[h], wbe[2 * h + 1], p1);
    }

    const float s = fmaf(p0, p0, fmaf(p1, p1, 1e-6f));
    const float inv = 1.0f / sqrtf(s);
    if (valid) {
        float2 o; o.x = p0 * inv; o.y = p1 * inv;
        ((float2*)out)[idx] = o;
    }
}

extern "C" void kernel_launch(void* const* d_in, const int* in_sizes, int n_in,
                              void* d_out, int out_size, void* d_ws, size_t ws_size,
                              hipStream_t stream) {
    const float* x  = (const float*)d_in[0];
    const int*   n  = (const int*)d_in[1];
    const int*   l  = (const int*)d_in[2];
    const int*   m  = (const int*)d_in[3];
    const float* W0 = (const float*)d_in[4];
    const float* b0 = (const float*)d_in[5];
    const float* W1 = (const float*)d_in[6];
    const float* b1 = (const float*)d_in[7];
    const float* Wa = (const float*)d_in[8];
    const float* ba = (const float*)d_in[9];
    const float* Wb = (const float*)d_in[10];
    const float* bb = (const float*)d_in[11];
    float* out = (float*)d_out;

    const int B = in_sizes[1];   // 262144

    // workspace layout (all segments 16B aligned)
    int*            done  = (int*)d_ws;                      // 1 (pad 32)
    int*            cnt   = done + 32;                       // HB*NE = 7680
    int*            etot  = cnt + HB * NE;                   // 30 (pad 32)
    int*            perm  = etot + 32;                       // B
    unsigned short* W1fh  = (unsigned short*)(perm + B);     // 8192 u16
    unsigned short* W1fl  = W1fh + 8192;                     // 8192 u16
    unsigned short* Wafh  = W1fl + 8192;                     // 30*2048 u16
    unsigned short* Wafl  = Wafh + NE * 2048;                // 30*2048 u16

    hipMemsetAsync(done, 0, sizeof(int), stream);
    fused_prologue<<<HB + 1 + NE, 256, 0, stream>>>(
        n, l, m, cnt, done, etot, perm, W1, W1fh, W1fl, Wa, Wafh, Wafl, B);
    wfc_kernel<<<MAXBLK, THREADS, 0, stream>>>(
        x, perm, etot, W0, b0,
        (const bf16x8*)W1fh, (const bf16x8*)W1fl, b1,
        (const bf16x8*)Wafh, (const bf16x8*)Wafl, ba, Wb, bb, out);
}